// Round 3
// baseline (349.210 us; speedup 1.0000x reference)
//
#include <hip/hip_runtime.h>

// Instant-NGP hash-grid trilinear interpolation, spatially-sorted edition.
//
// Bottleneck (R1/R2 evidence): L2-miss stream of the random 32B row gathers.
// 612 MB FETCH @ ~3.1 TB/s, VALUBusy <7%, occupancy 78% -> the kernel is
// bound by L2 misses, not by instruction issue (pairing VMEM ops was neutral).
// Fix: process points in spatial (Morton-tile) order so repeated accesses to
// the same lattice row (avg ~4.7 accesses/row) hit L2 instead of re-missing.
//
// Pipeline (all on `stream`, graph-capturable):
//   memset bins -> hist -> block-scan -> partials-scan -> scatter(sorted pts)
//   -> main gather kernel over sorted points (XCD-chunked block swizzle).
// Per-point arithmetic is identical to the verified R1 kernel; sorting only
// permutes processing order, and each point writes its own output row, so the
// output is bit-identical and deterministic.

#define TILE_SHIFT 2                    // tile = 4^3 cells
#define MBITS 6                         // tiles/dim <= 64 (actual 50)
#define NBINS (1u << (3 * MBITS))       // 262144 bins
#define SCAN_BLOCK 256
#define NPARTIALS (NBINS / SCAN_BLOCK)  // 1024

__device__ __forceinline__ unsigned part1by2(unsigned x) {
    x &= 0x3Fu;
    x = (x | (x << 16)) & 0x030000FFu;
    x = (x | (x << 8))  & 0x0300F00Fu;
    x = (x | (x << 4))  & 0x030C30C3u;
    x = (x | (x << 2))  & 0x09249249u;
    return x;
}

__device__ __forceinline__ unsigned point_bin(float px, float py, float pz) {
    // Same divide+floor as the main kernel so binning is consistent.
    float qx = px / 0.005f, qy = py / 0.005f, qz = pz / 0.005f;
    int cx = (int)floorf(qx), cy = (int)floorf(qy), cz = (int)floorf(qz);
    unsigned tx = ((unsigned)cx) >> TILE_SHIFT;
    unsigned ty = ((unsigned)cy) >> TILE_SHIFT;
    unsigned tz = ((unsigned)cz) >> TILE_SHIFT;
    return part1by2(tx) | (part1by2(ty) << 1) | (part1by2(tz) << 2);
}

__global__ __launch_bounds__(256) void hist_kernel(
    const float* __restrict__ pts, unsigned* __restrict__ bins, int N)
{
    int i = blockIdx.x * blockDim.x + threadIdx.x;
    if (i >= N) return;
    unsigned b = point_bin(pts[3*i], pts[3*i+1], pts[3*i+2]);
    atomicAdd(&bins[b], 1u);
}

// Per-block exclusive scan of bins (in place), block totals -> partials.
__global__ __launch_bounds__(SCAN_BLOCK) void scan_blocks_kernel(
    unsigned* __restrict__ bins, unsigned* __restrict__ partials)
{
    __shared__ unsigned s[SCAN_BLOCK];
    int t = threadIdx.x;
    int g = blockIdx.x * SCAN_BLOCK + t;
    unsigned v = bins[g];
    s[t] = v;
    __syncthreads();
    #pragma unroll
    for (int d = 1; d < SCAN_BLOCK; d <<= 1) {
        unsigned add = (t >= d) ? s[t - d] : 0u;
        __syncthreads();
        s[t] += add;
        __syncthreads();
    }
    bins[g] = s[t] - v;                       // exclusive within block
    if (t == SCAN_BLOCK - 1) partials[blockIdx.x] = s[t];
}

// Exclusive scan of the 1024 block totals, in place. Single block.
__global__ __launch_bounds__(SCAN_BLOCK) void scan_partials_kernel(
    unsigned* __restrict__ partials)
{
    __shared__ unsigned s[SCAN_BLOCK];
    int t = threadIdx.x;
    unsigned v[4], sum = 0u;
    #pragma unroll
    for (int j = 0; j < 4; ++j) { v[j] = partials[4*t + j]; sum += v[j]; }
    s[t] = sum;
    __syncthreads();
    #pragma unroll
    for (int d = 1; d < SCAN_BLOCK; d <<= 1) {
        unsigned add = (t >= d) ? s[t - d] : 0u;
        __syncthreads();
        s[t] += add;
        __syncthreads();
    }
    unsigned run = s[t] - sum;                // exclusive base for this thread
    #pragma unroll
    for (int j = 0; j < 4; ++j) { partials[4*t + j] = run; run += v[j]; }
}

// Scatter points (coords + original index) into sorted order.
__global__ __launch_bounds__(256) void scatter_kernel(
    const float* __restrict__ pts, unsigned* __restrict__ bins,
    const unsigned* __restrict__ partials, float4* __restrict__ sorted, int N)
{
    int i = blockIdx.x * blockDim.x + threadIdx.x;
    if (i >= N) return;
    float px = pts[3*i], py = pts[3*i+1], pz = pts[3*i+2];
    unsigned b = point_bin(px, py, pz);
    unsigned pos = partials[b >> 8] + atomicAdd(&bins[b], 1u);
    float4 e; e.x = px; e.y = py; e.z = pz; e.w = __uint_as_float((unsigned)i);
    sorted[pos] = e;
}

// Main gather kernel: 2 threads per (sorted) point, paired 16B halves.
__global__ __launch_bounds__(256) void ngp_hash_interp_sorted(
    const float4* __restrict__ sorted,
    const float4* __restrict__ feat4,
    float4* __restrict__ out4,
    int N, unsigned buckets, int is_pow2, int nwg)
{
    // XCD-chunked bijective block swizzle (m204): contiguous sorted chunk per XCD.
    int orig = blockIdx.x;
    int q = nwg >> 3, r = nwg & 7;
    int xcd = orig & 7, lq = orig >> 3;
    int bid = (xcd < r ? xcd * (q + 1) : r * (q + 1) + (xcd - r) * q) + lq;

    int t = bid * 256 + (int)threadIdx.x;
    int i = t >> 1;
    unsigned h = (unsigned)(t & 1);
    if (i >= N) return;

    float4 e = sorted[i];
    float px = e.x, py = e.y, pz = e.z;
    unsigned oidx = __float_as_uint(e.w);

    float qx = px / 0.005f, qy = py / 0.005f, qz = pz / 0.005f;
    float bx = floorf(qx), by = floorf(qy), bz = floorf(qz);
    float fx = qx - bx, fy = qy - by, fz = qz - bz;

    unsigned ux = (unsigned)(int)bx;
    unsigned uy = (unsigned)(int)by;
    unsigned uz = (unsigned)(int)bz;

    unsigned hx0 = ux, hx1 = ux + 1u;
    unsigned hy0 = uy * 2654435761u, hy1 = (uy + 1u) * 2654435761u;
    unsigned hz0 = uz * 805459861u,  hz1 = (uz + 1u) * 805459861u;

    unsigned hsh[8] = {
        hx0 ^ hy0 ^ hz0, hx1 ^ hy0 ^ hz0,
        hx0 ^ hy1 ^ hz0, hx1 ^ hy1 ^ hz0,
        hx0 ^ hy0 ^ hz1, hx1 ^ hy0 ^ hz1,
        hx0 ^ hy1 ^ hz1, hx1 ^ hy1 ^ hz1,
    };

    unsigned off[8];
    if (is_pow2) {
        unsigned mask = buckets - 1u;
        #pragma unroll
        for (int c = 0; c < 8; ++c) off[c] = (hsh[c] & mask) * 2u + h;
    } else {
        #pragma unroll
        for (int c = 0; c < 8; ++c) off[c] = (hsh[c] % buckets) * 2u + h;
    }

    float4 f[8];
    #pragma unroll
    for (int c = 0; c < 8; ++c) f[c] = feat4[off[c]];

    float wx0 = 1.0f - fx, wx1 = fx;
    float wy0 = 1.0f - fy, wy1 = fy;
    float wz0 = 1.0f - fz, wz1 = fz;
    float w[8] = {
        (wx0 * wy0) * wz0, (wx1 * wy0) * wz0,
        (wx0 * wy1) * wz0, (wx1 * wy1) * wz0,
        (wx0 * wy0) * wz1, (wx1 * wy0) * wz1,
        (wx0 * wy1) * wz1, (wx1 * wy1) * wz1,
    };

    float4 a = make_float4(0.f, 0.f, 0.f, 0.f);
    #pragma unroll
    for (int c = 0; c < 8; ++c) {
        a.x += w[c] * f[c].x;
        a.y += w[c] * f[c].y;
        a.z += w[c] * f[c].z;
        a.w += w[c] * f[c].w;
    }

    out4[(size_t)oidx * 2u + h] = a;
}

// Fallback (verified R1 kernel) if ws is too small.
__global__ __launch_bounds__(256) void ngp_hash_interp2(
    const float* __restrict__ pts,
    const float4* __restrict__ feat4,
    float4* __restrict__ out4,
    int N, unsigned buckets, int is_pow2)
{
    int t = blockIdx.x * blockDim.x + threadIdx.x;
    int i = t >> 1;
    unsigned h = (unsigned)(t & 1);
    if (i >= N) return;

    float px = pts[3*i], py = pts[3*i+1], pz = pts[3*i+2];
    float qx = px / 0.005f, qy = py / 0.005f, qz = pz / 0.005f;
    float bx = floorf(qx), by = floorf(qy), bz = floorf(qz);
    float fx = qx - bx, fy = qy - by, fz = qz - bz;
    unsigned ux = (unsigned)(int)bx, uy = (unsigned)(int)by, uz = (unsigned)(int)bz;
    unsigned hx0 = ux, hx1 = ux + 1u;
    unsigned hy0 = uy * 2654435761u, hy1 = (uy + 1u) * 2654435761u;
    unsigned hz0 = uz * 805459861u,  hz1 = (uz + 1u) * 805459861u;
    unsigned hsh[8] = {
        hx0 ^ hy0 ^ hz0, hx1 ^ hy0 ^ hz0,
        hx0 ^ hy1 ^ hz0, hx1 ^ hy1 ^ hz0,
        hx0 ^ hy0 ^ hz1, hx1 ^ hy0 ^ hz1,
        hx0 ^ hy1 ^ hz1, hx1 ^ hy1 ^ hz1,
    };
    unsigned off[8];
    if (is_pow2) {
        unsigned mask = buckets - 1u;
        #pragma unroll
        for (int c = 0; c < 8; ++c) off[c] = (hsh[c] & mask) * 2u + h;
    } else {
        #pragma unroll
        for (int c = 0; c < 8; ++c) off[c] = (hsh[c] % buckets) * 2u + h;
    }
    float4 f[8];
    #pragma unroll
    for (int c = 0; c < 8; ++c) f[c] = feat4[off[c]];
    float wx0 = 1.0f - fx, wx1 = fx;
    float wy0 = 1.0f - fy, wy1 = fy;
    float wz0 = 1.0f - fz, wz1 = fz;
    float w[8] = {
        (wx0 * wy0) * wz0, (wx1 * wy0) * wz0,
        (wx0 * wy1) * wz0, (wx1 * wy1) * wz0,
        (wx0 * wy0) * wz1, (wx1 * wy0) * wz1,
        (wx0 * wy1) * wz1, (wx1 * wy1) * wz1,
    };
    float4 a = make_float4(0.f, 0.f, 0.f, 0.f);
    #pragma unroll
    for (int c = 0; c < 8; ++c) {
        a.x += w[c] * f[c].x;
        a.y += w[c] * f[c].y;
        a.z += w[c] * f[c].z;
        a.w += w[c] * f[c].w;
    }
    out4[(size_t)i * 2u + h] = a;
}

extern "C" void kernel_launch(void* const* d_in, const int* in_sizes, int n_in,
                              void* d_out, int out_size, void* d_ws, size_t ws_size,
                              hipStream_t stream) {
    const float* pts   = (const float*)d_in[0];
    const float4* feat4 = (const float4*)d_in[1];
    float4* out4 = (float4*)d_out;

    int N = in_sizes[0] / 3;
    unsigned buckets = (unsigned)(in_sizes[1] / 8);
    int is_pow2 = ((buckets & (buckets - 1u)) == 0u) ? 1 : 0;

    // ws layout: sorted float4[N] | bins u32[NBINS] | partials u32[NPARTIALS]
    size_t need = (size_t)N * 16 + (size_t)NBINS * 4 + (size_t)NPARTIALS * 4;
    if (ws_size < need) {
        const int block = 256;
        const long long total = 2LL * N;
        const int grid = (int)((total + block - 1) / block);
        hipLaunchKernelGGL(ngp_hash_interp2, dim3(grid), dim3(block), 0, stream,
                           pts, feat4, out4, N, buckets, is_pow2);
        return;
    }

    float4* sorted = (float4*)d_ws;
    unsigned* bins = (unsigned*)((char*)d_ws + (size_t)N * 16);
    unsigned* partials = bins + NBINS;

    hipMemsetAsync(bins, 0, (size_t)NBINS * 4, stream);

    const int block = 256;
    int gridN = (N + block - 1) / block;
    hipLaunchKernelGGL(hist_kernel, dim3(gridN), dim3(block), 0, stream,
                       pts, bins, N);
    hipLaunchKernelGGL(scan_blocks_kernel, dim3(NBINS / SCAN_BLOCK), dim3(SCAN_BLOCK),
                       0, stream, bins, partials);
    hipLaunchKernelGGL(scan_partials_kernel, dim3(1), dim3(SCAN_BLOCK), 0, stream,
                       partials);
    hipLaunchKernelGGL(scatter_kernel, dim3(gridN), dim3(block), 0, stream,
                       pts, bins, partials, sorted, N);

    long long total = 2LL * N;
    int nwg = (int)((total + block - 1) / block);
    hipLaunchKernelGGL(ngp_hash_interp_sorted, dim3(nwg), dim3(block), 0, stream,
                       sorted, feat4, out4, N, buckets, is_pow2, nwg);
}